// Round 4
// baseline (136.886 us; speedup 1.0000x reference)
//
#include <hip/hip_runtime.h>
#include <stdint.h>

#define SEQ 8192
#define DIN 768
#define DOUT 128

typedef __attribute__((ext_vector_type(8))) short short8;
typedef __attribute__((ext_vector_type(8))) unsigned short ushort8v;
typedef __attribute__((ext_vector_type(4))) float f32x4;

// softmax exp base conversion: (1/sqrt(128)) * log2(e), folded into wq at convert time
#define CEXPF (1.4426950408889634f * 0.08838834764831845f)

#if __has_builtin(__builtin_amdgcn_exp2f)
#define EXP2(x) __builtin_amdgcn_exp2f(x)
#else
#define EXP2(x) __builtin_exp2f(x)
#endif

// round-half-up f32->bf16 (2 VALU ops)
__device__ __forceinline__ unsigned short f2bf(float f) {
  return (unsigned short)((__float_as_uint(f) + 0x8000u) >> 16);
}

// async global->LDS DMA, 16B per lane.  LDS dest = wave-uniform base + lane*16.
__device__ __forceinline__ void gload_lds16(const void* g, void* l) {
  __builtin_amdgcn_global_load_lds(
      (const __attribute__((address_space(1))) void*)g,
      (__attribute__((address_space(3))) void*)l, 16, 0, 0);
}

// ---------------------------------------------------------------------------
// Kernel 0: fp32 -> bf16 convert of x AND the three W's (wq scaled by CEXPF).
// xb[8192][768], Wb[z][128][768].  grid 6432, block 256, 4 elems/thread.
// ---------------------------------------------------------------------------
#define XELEMS (SEQ * DIN)          // 6291456
#define WELEMS (DOUT * DIN)         // 98304
__global__ void conv_kernel(const float* __restrict__ x,
                            const float* __restrict__ wq,
                            const float* __restrict__ wk,
                            const float* __restrict__ wv,
                            unsigned short* __restrict__ xb,
                            unsigned short* __restrict__ Wb) {
  int idx4 = (blockIdx.x * 256 + threadIdx.x) * 4;
  const float* src;
  unsigned short* dst;
  float sc = 1.0f;
  if (idx4 < XELEMS) {
    src = x + idx4;
    dst = xb + idx4;
  } else {
    int wi = idx4 - XELEMS;               // < 3*98304
    int z  = wi / WELEMS;
    int rem = wi - z * WELEMS;
    src = ((z == 0) ? wq : (z == 1) ? wk : wv) + rem;
    dst = Wb + wi;
    if (z == 0) sc = CEXPF;
  }
  float4 v = *(const float4*)src;
  ushort4 o;
  o.x = f2bf(v.x * sc); o.y = f2bf(v.y * sc);
  o.z = f2bf(v.z * sc); o.w = f2bf(v.w * sc);
  *(ushort4*)dst = o;
}

// ---------------------------------------------------------------------------
// Kernel A: QKV projection, m97-style bf16 GEMM.  grid (64, 3), block 256.
// Tile: 128 seqrows x 128 outcols, BK=64 (12 iters).  Both tiles staged via
// global_load_lds w/ source-side XOR swizzle.  A=W (m=outcol), B=x (n=seqrow)
// -> D col = seqrow = r: each lane holds 4 consecutive outcols -> ushort4
// epilogue stores.  z=2 transposes through LDS into Vt[128][8192].
// ---------------------------------------------------------------------------
__launch_bounds__(256, 2)
__global__ void qkv_kernel(const unsigned short* __restrict__ xb,
                           const unsigned short* __restrict__ Wb,
                           unsigned short* __restrict__ Qb,
                           unsigned short* __restrict__ Kb,
                           unsigned short* __restrict__ Vtb) {
  __shared__ unsigned char lds_u[35072];
  unsigned char* xs = lds_u;            // [128 seqrow][64 k] bf16, 8 chunks/row XOR-swz
  unsigned char* ws = lds_u + 16384;    // [128 outcol][64 k] bf16, same layout

  const int t    = threadIdx.x;
  const int w    = t >> 6;
  const int lane = t & 63;
  const int g    = lane >> 4;
  const int r    = lane & 15;
  const int z    = blockIdx.y;
  const int m0   = blockIdx.x * 128;
  const unsigned short* Wz = Wb + (size_t)z * WELEMS;

  f32x4 acc[2][8];
#pragma unroll
  for (int i = 0; i < 2; i++)
#pragma unroll
    for (int j = 0; j < 8; j++) acc[i][j] = 0.f;

#pragma unroll 1
  for (int kb = 0; kb < DIN; kb += 64) {
    // ---- DMA staging: x tile 128x64 + W tile 128x64, source-side XOR swizzle
#pragma unroll
    for (int c = 0; c < 4; c++) {
      int ci = (w * 4 + c) * 64 + lane;         // 0..1023
      int row = ci >> 3, ch = ci & 7;           // chunk = 8 bf16
      int sch = ch ^ (row & 7);
      gload_lds16(xb + (size_t)(m0 + row) * DIN + kb + sch * 8,
                  xs + ((w * 4 + c) << 10) + (lane << 4));
      gload_lds16(Wz + (size_t)row * DIN + kb + sch * 8,
                  ws + ((w * 4 + c) << 10) + (lane << 4));
    }
    __syncthreads();

    // ---- frags + MFMA: wave w owns outcols [w*32, w*32+32), all 128 seqrows
    short8 af[2][2], bf[2];
#pragma unroll
    for (int mt = 0; mt < 2; mt++)
#pragma unroll
      for (int kc = 0; kc < 2; kc++) {
        int row = w * 32 + mt * 16 + r;
        af[mt][kc] = *(const short8*)(ws + row * 128 + (((kc * 4 + g) ^ (r & 7)) << 4));
      }
#pragma unroll
    for (int nt = 0; nt < 8; nt++) {
      int row = nt * 16 + r;
#pragma unroll
      for (int kc = 0; kc < 2; kc++)
        bf[kc] = *(const short8*)(xs + row * 128 + (((kc * 4 + g) ^ (r & 7)) << 4));
#pragma unroll
      for (int mt = 0; mt < 2; mt++) {
        acc[mt][nt] = __builtin_amdgcn_mfma_f32_16x16x32_bf16(af[mt][0], bf[0], acc[mt][nt], 0, 0, 0);
        acc[mt][nt] = __builtin_amdgcn_mfma_f32_16x16x32_bf16(af[mt][1], bf[1], acc[mt][nt], 0, 0, 0);
      }
    }
    __syncthreads();
  }

  // D[m = w*32+mt*16+g*4+reg (outcol)][n = nt*16+r (seqrow)]
  if (z < 2) {
    unsigned short* out = (z == 0) ? Qb : Kb;
#pragma unroll
    for (int mt = 0; mt < 2; mt++)
#pragma unroll
      for (int nt = 0; nt < 8; nt++) {
        ushort4 o;
        o.x = f2bf(acc[mt][nt][0]); o.y = f2bf(acc[mt][nt][1]);
        o.z = f2bf(acc[mt][nt][2]); o.w = f2bf(acc[mt][nt][3]);
        *(ushort4*)(out + (size_t)(m0 + nt * 16 + r) * DOUT + w * 32 + mt * 16 + g * 4) = o;
      }
  } else {
    unsigned short* ct = (unsigned short*)lds_u;   // [128 seqrow][136]
#pragma unroll
    for (int mt = 0; mt < 2; mt++)
#pragma unroll
      for (int nt = 0; nt < 8; nt++) {
        ushort4 o;
        o.x = f2bf(acc[mt][nt][0]); o.y = f2bf(acc[mt][nt][1]);
        o.z = f2bf(acc[mt][nt][2]); o.w = f2bf(acc[mt][nt][3]);
        *(ushort4*)&ct[(nt * 16 + r) * 136 + w * 32 + mt * 16 + g * 4] = o;
      }
    __syncthreads();
    int col  = t >> 1;            // outcol 0..127
    int half = (t & 1) * 64;      // seqrow half
#pragma unroll
    for (int h = 0; h < 8; h++) {
      ushort8v a;
#pragma unroll
      for (int i = 0; i < 8; i++) a[i] = ct[(half + h * 8 + i) * 136 + col];
      *(ushort8v*)(Vtb + (size_t)col * SEQ + m0 + half + h * 8) = a;
    }
  }
}

// ---------------------------------------------------------------------------
// Kernel B: flash attention (no online max; scale folded into Q).
// grid (64 qblocks, 8 splits), block 256 (4 waves), wave = 32 q-rows, BN=64.
// ---------------------------------------------------------------------------
__launch_bounds__(256, 2)
__global__ void attn_kernel(const unsigned short* __restrict__ Qb,
                            const unsigned short* __restrict__ Kb,
                            const unsigned short* __restrict__ Vtb,
                            float* __restrict__ Opart,
                            float* __restrict__ lpart) {
  __shared__ unsigned char lds[51200];
  unsigned char* Kl = lds;           // [64][128] bf16, 16B chunks XOR-swizzled by row&15
  unsigned char* Vl = lds + 16384;   // [128][64] bf16, 16B chunks XOR-swizzled by d&7

  const int t    = threadIdx.x;
  const int wave = t >> 6;
  const int lane = t & 63;
  const int g    = lane >> 4;
  const int r    = lane & 15;
  unsigned short* Pl = (unsigned short*)(lds + 32768 + wave * 4608);  // [32 q][72 kv]

  const int qb = blockIdx.x;
  const int sp = blockIdx.y;
  const int q0 = qb * 128 + wave * 32;

  short8 qf[2][4];
#pragma unroll
  for (int nt = 0; nt < 2; nt++)
#pragma unroll
    for (int kc = 0; kc < 4; kc++)
      qf[nt][kc] = *(const short8*)(Qb + (size_t)(q0 + nt * 16 + r) * DOUT + kc * 32 + g * 8);

  short8 onesf;
#pragma unroll
  for (int j = 0; j < 8; j++) onesf[j] = (r == 0) ? (short)0x3F80 : (short)0;

  f32x4 oacc[2][8];
  f32x4 lacc[2];
#pragma unroll
  for (int st = 0; st < 2; st++) {
    lacc[st] = 0.f;
#pragma unroll
    for (int n = 0; n < 8; n++) oacc[st][n] = 0.f;
  }

#pragma unroll 1
  for (int it = 0; it < 16; it++) {
    const int kv0 = sp * 1024 + it * 64;
#pragma unroll
    for (int c = 0; c < 4; c++) {
      int idx = (wave * 4 + c) * 64 + lane;
      int krow = idx >> 4, kch = idx & 15;
      gload_lds16(Kb + ((size_t)(kv0 + krow) << 7) + ((kch ^ (krow & 15)) << 3),
                  Kl + ((wave * 4 + c) << 10) + (lane << 4));
      int d = idx >> 3, c2 = idx & 7;
      gload_lds16(Vtb + (size_t)d * SEQ + kv0 + ((c2 ^ (d & 7)) << 3),
                  Vl + ((wave * 4 + c) << 10) + (lane << 4));
    }
    __syncthreads();

    f32x4 sf[4][2];
#pragma unroll
    for (int mt = 0; mt < 4; mt++)
#pragma unroll
      for (int nt = 0; nt < 2; nt++) sf[mt][nt] = 0.f;
#pragma unroll
    for (int mt = 0; mt < 4; mt++) {
      int row = mt * 16 + r;
#pragma unroll
      for (int kc = 0; kc < 4; kc++) {
        short8 kf = *(const short8*)(Kl + row * 256 + (((kc * 4 + g) ^ (row & 15)) << 4));
        sf[mt][0] = __builtin_amdgcn_mfma_f32_16x16x32_bf16(kf, qf[0][kc], sf[mt][0], 0, 0, 0);
        sf[mt][1] = __builtin_amdgcn_mfma_f32_16x16x32_bf16(kf, qf[1][kc], sf[mt][1], 0, 0, 0);
      }
    }

#pragma unroll
    for (int mt = 0; mt < 4; mt++)
#pragma unroll
      for (int nt = 0; nt < 2; nt++) {
        ushort4 p;
        p.x = f2bf(EXP2(sf[mt][nt][0]));
        p.y = f2bf(EXP2(sf[mt][nt][1]));
        p.z = f2bf(EXP2(sf[mt][nt][2]));
        p.w = f2bf(EXP2(sf[mt][nt][3]));
        *(ushort4*)(Pl + (nt * 16 + r) * 72 + mt * 16 + g * 4) = p;
      }
    short8 pf[2][2];
#pragma unroll
    for (int st = 0; st < 2; st++)
#pragma unroll
      for (int c2 = 0; c2 < 2; c2++)
        pf[st][c2] = *(const short8*)(Pl + (st * 16 + r) * 72 + c2 * 32 + g * 8);

#pragma unroll
    for (int nt = 0; nt < 8; nt++) {
      int d = nt * 16 + r;
#pragma unroll
      for (int c2 = 0; c2 < 2; c2++) {
        short8 vf = *(const short8*)(Vl + d * 128 + (((c2 * 4 + g) ^ (d & 7)) << 4));
        oacc[0][nt] = __builtin_amdgcn_mfma_f32_16x16x32_bf16(pf[0][c2], vf, oacc[0][nt], 0, 0, 0);
        oacc[1][nt] = __builtin_amdgcn_mfma_f32_16x16x32_bf16(pf[1][c2], vf, oacc[1][nt], 0, 0, 0);
      }
    }
#pragma unroll
    for (int st = 0; st < 2; st++) {
      lacc[st] = __builtin_amdgcn_mfma_f32_16x16x32_bf16(pf[st][0], onesf, lacc[st], 0, 0, 0);
      lacc[st] = __builtin_amdgcn_mfma_f32_16x16x32_bf16(pf[st][1], onesf, lacc[st], 0, 0, 0);
    }
    __syncthreads();
  }

  const size_t pbase = (size_t)sp * SEQ;
#pragma unroll
  for (int st = 0; st < 2; st++)
#pragma unroll
    for (int rr = 0; rr < 4; rr++) {
      int qrow = q0 + st * 16 + g * 4 + rr;
#pragma unroll
      for (int nt = 0; nt < 8; nt++)
        Opart[(pbase + qrow) * DOUT + nt * 16 + r] = oacc[st][nt][rr];
      if (r == 0) lpart[pbase + qrow] = lacc[st][rr];
    }
}

// ---------------------------------------------------------------------------
// Kernel C: combine 8 KV-split partials (plain sum + normalize).
// ---------------------------------------------------------------------------
__global__ void combine_kernel(const float* __restrict__ Opart,
                               const float* __restrict__ lpart,
                               float* __restrict__ out) {
  int idx = blockIdx.x * 256 + threadIdx.x;  // 8192*32
  int s   = idx >> 5;
  int d4  = (idx & 31) * 4;
  float L = 0.f;
  f32x4 acc = 0.f;
#pragma unroll
  for (int p = 0; p < 8; p++) {
    L += lpart[p * SEQ + s];
    acc += *(const f32x4*)(Opart + ((size_t)p * SEQ + s) * DOUT + d4);
  }
  f32x4 res = acc * (1.0f / L);
  *(f32x4*)(out + (size_t)s * DOUT + d4) = res;
}

// ---------------------------------------------------------------------------
extern "C" void kernel_launch(void* const* d_in, const int* in_sizes, int n_in,
                              void* d_out, int out_size, void* d_ws, size_t ws_size,
                              hipStream_t stream) {
  const float* x  = (const float*)d_in[0];
  const float* wq = (const float*)d_in[1];
  const float* wk = (const float*)d_in[2];
  const float* wv = (const float*)d_in[3];
  float* out = (float*)d_out;

  unsigned short* Qb  = (unsigned short*)d_ws;            // 2 MB
  unsigned short* Kb  = Qb + (size_t)SEQ * DOUT;          // 2 MB
  unsigned short* Vtb = Kb + (size_t)SEQ * DOUT;          // 2 MB (transposed)
  float* Opart = (float*)(Vtb + (size_t)SEQ * DOUT);      // 8 * 4 MB
  float* lpart = Opart + (size_t)8 * SEQ * DOUT;          // 256 KB
  // xb (12.6 MB) + Wb (0.58 MB) alias Opart: dead before attn writes it
  unsigned short* xb = (unsigned short*)Opart;
  unsigned short* Wb = xb + (size_t)XELEMS;
  if (ws_size < (size_t)(6291456 + 33554432 + 262144)) return;

  conv_kernel<<<dim3(6432), 256, 0, stream>>>(x, wq, wk, wv, xb, Wb);
  qkv_kernel<<<dim3(64, 3), 256, 0, stream>>>(xb, Wb, Qb, Kb, Vtb);
  attn_kernel<<<dim3(64, 8), 256, 0, stream>>>(Qb, Kb, Vtb, Opart, lpart);
  combine_kernel<<<dim3(1024), 256, 0, stream>>>(Opart, lpart, out);
}